// Round 17
// baseline (864.752 us; speedup 1.0000x reference)
//
#include <hip/hip_runtime.h>
#include <hip/hip_bf16.h>
#include <cstddef>

typedef unsigned short u16;
typedef unsigned int u32;
typedef short bf16x8 __attribute__((ext_vector_type(8)));
typedef unsigned short u16x8 __attribute__((ext_vector_type(8)));
typedef float f32x4 __attribute__((ext_vector_type(4)));
typedef int i32x4 __attribute__((ext_vector_type(4)));
typedef int i32x8 __attribute__((ext_vector_type(8)));

constexpr int CB = 128;    // batch
constexpr int CT = 512;    // time
constexpr int CE = 128;    // embed dim
constexpr int CK = 20;     // tags

// ---- workspace layout (bytes) ----
constexpr size_t OFF_FLAG   = 0;                      // int dtype flag (1=bf16 inputs)
constexpr size_t OFF_WIH0   = 256;                    // bf16 [1024][128]
constexpr size_t OFF_WHH0   = OFF_WIH0 + 262144;      // bf16 [1024][128]
constexpr size_t OFF_WIH1   = OFF_WHH0 + 262144;      // bf16 [1024][256]
constexpr size_t OFF_WHH1   = OFF_WIH1 + 524288;      // bf16 [1024][128]
constexpr size_t OFF_WOUT   = OFF_WHH1 + 262144;      // bf16 [20][256]
constexpr size_t OFF_B0     = OFF_WOUT + 10240;       // f32 [1024]
constexpr size_t OFF_B1     = OFF_B0 + 4096;          // f32 [1024]
constexpr size_t OFF_BOUT   = OFF_B1 + 4096;          // f32 [20]
constexpr size_t OFF_TRANS  = OFF_BOUT + 256;         // f32 [400]
constexpr size_t OFF_START  = OFF_TRANS + 1792;       // f32 [20]
constexpr size_t OFF_END    = OFF_START + 256;        // f32 [20]
constexpr size_t OFF_PART   = OFF_END + 256;          // f32 [256]: logZ[128], score[128]
constexpr size_t OFF_WHH0F8 = OFF_PART + 256;         // fp8 e4m3 (x8-scaled) [1024][128]
constexpr size_t OFF_WHH1F8 = OFF_WHH0F8 + 131072;    // fp8 e4m3 (x8-scaled) [1024][128]
constexpr size_t OFF_X0     = 2097152;                // bf16 [65536][128]
constexpr size_t OFF_H0     = OFF_X0 + 16777216;      // bf16 [65536][256]
constexpr size_t OFF_H1     = OFF_H0 + 33554432;      // bf16 [65536][256]
constexpr size_t OFF_EM     = OFF_H1 + 33554432;      // f32  [65536][20]
constexpr size_t OFF_Z      = OFF_EM + 5242880;       // bf16 Z[t_scan][seq=b*2+d][512] t-major, bias-folded
constexpr size_t WS_NEED    = OFF_Z + 134217728;      // ~225.4 MB

__device__ __forceinline__ float b2f(u16 u) {
    union { u32 i; float f; } v; v.i = ((u32)u) << 16; return v.f;
}
__device__ __forceinline__ u16 f2b(float f) {
    union { float f; u32 i; } v; v.f = f;
    u32 r = v.i + 0x7FFFu + ((v.i >> 16) & 1u);   // RNE
    return (u16)(r >> 16);
}
__device__ __forceinline__ float ldin(const void* p, long i, int bf) {
    return bf ? b2f(((const u16*)p)[i]) : ((const float*)p)[i];
}
__device__ __forceinline__ float sigm(float x) { return 1.0f / (1.0f + __expf(-x)); }
__device__ __forceinline__ float tanh_f(float x) { return 2.0f / (1.0f + __expf(-2.0f * x)) - 1.0f; }

// async global -> LDS, 16 B per lane. dest must be wave-uniform base (HW adds lane*16).
__device__ __forceinline__ void gload_lds16(const void* g, void* l) {
    __builtin_amdgcn_global_load_lds(
        (const __attribute__((address_space(1))) void*)g,
        (__attribute__((address_space(3))) void*)l, 16, 0, 0);
}

// ---- detect whether float inputs are bf16 or f32, from `trans` ----
__global__ void sniff_k(const unsigned char* __restrict__ traw, int* __restrict__ flag) {
    int lane = threadIdx.x;
    int votes = 0;
    for (int w = lane; w < 200; w += 64) {
        unsigned char b1 = traw[w * 4 + 1];
        unsigned char e = b1 & 0x7F;
        if (e >= 0x20 && e <= 0x3E) votes++;
    }
    #pragma unroll
    for (int off = 32; off; off >>= 1) votes += __shfl_xor(votes, off);
    if (lane == 0) *flag = (votes > 120) ? 1 : 0;
}

// ---- convert all weights into canonical ws copies ----
__global__ __launch_bounds__(256) void prep_k(
    const void* wih0, const void* whh0, const void* b0,
    const void* wih1, const void* whh1, const void* b1,
    const void* wout, const void* bout, const void* trans,
    const void* start, const void* end, unsigned char* ws)
{
    const int bf = *(const int*)(ws + OFF_FLAG);
    long tid = (long)blockIdx.x * 256 + threadIdx.x;
    u16* wih0b = (u16*)(ws + OFF_WIH0);
    u16* whh0b = (u16*)(ws + OFF_WHH0);
    u16* wih1b = (u16*)(ws + OFF_WIH1);
    u16* whh1b = (u16*)(ws + OFF_WHH1);
    u16* woutb = (u16*)(ws + OFF_WOUT);
    float* b0f   = (float*)(ws + OFF_B0);
    float* b1f   = (float*)(ws + OFF_B1);
    float* boutf = (float*)(ws + OFF_BOUT);
    float* trf   = (float*)(ws + OFF_TRANS);
    float* stf   = (float*)(ws + OFF_START);
    float* enf   = (float*)(ws + OFF_END);

    if (tid < 131072) { wih0b[tid] = f2b(ldin(wih0, tid, bf)); return; } tid -= 131072;
    if (tid < 131072) { whh0b[tid] = f2b(ldin(whh0, tid, bf)); return; } tid -= 131072;
    if (tid < 1024)   { b0f[tid]   = ldin(b0, tid, bf);        return; } tid -= 1024;
    if (tid < 262144) { wih1b[tid] = f2b(ldin(wih1, tid, bf)); return; } tid -= 262144;
    if (tid < 131072) { whh1b[tid] = f2b(ldin(whh1, tid, bf)); return; } tid -= 131072;
    if (tid < 1024)   { b1f[tid]   = ldin(b1, tid, bf);        return; } tid -= 1024;
    if (tid < 5120)   { woutb[tid] = f2b(ldin(wout, tid, bf)); return; } tid -= 5120;
    if (tid < 20)     { boutf[tid] = ldin(bout, tid, bf);      return; } tid -= 20;
    if (tid < 400)    { trf[tid]   = ldin(trans, tid, bf);     return; } tid -= 400;
    if (tid < 20)     { stf[tid]   = ldin(start, tid, bf);     return; } tid -= 20;
    if (tid < 20)     { enf[tid]   = ldin(end, tid, bf);       return; } tid -= 20;
    // fp8 e4m3 (x8-scaled) copies of Whh for the scan's MX MFMA
    if (tid < 65536) {
        const float v0 = ldin(whh0, tid * 2, bf) * 8.0f;
        const float v1 = ldin(whh0, tid * 2 + 1, bf) * 8.0f;
        const u32 pk = __builtin_amdgcn_cvt_pk_fp8_f32(v0, v1, 0, false);
        ((u16*)(ws + OFF_WHH0F8))[tid] = (u16)(pk & 0xFFFF);
        return;
    } tid -= 65536;
    if (tid < 65536) {
        const float v0 = ldin(whh1, tid * 2, bf) * 8.0f;
        const float v1 = ldin(whh1, tid * 2 + 1, bf) * 8.0f;
        const u32 pk = __builtin_amdgcn_cvt_pk_fp8_f32(v0, v1, 0, false);
        ((u16*)(ws + OFF_WHH1F8))[tid] = (u16)(pk & 0xFFFF);
        return;
    }
}

// ---- embedding gather -> x0 bf16 [m = t*CB+b][128] ----
__global__ __launch_bounds__(256) void gather_k(const void* __restrict__ embed,
                                                const int* __restrict__ sent,
                                                unsigned char* __restrict__ ws)
{
    const int bf = *(const int*)(ws + OFF_FLAG);
    u16* x0 = (u16*)(ws + OFF_X0);
    int tid = blockIdx.x * 256 + threadIdx.x;      // 1,048,576 threads
    int m = tid >> 4, ch = tid & 15;
    int t = m >> 7, b = m & 127;
    int s = sent[b * CT + t];
    long src = (long)s * CE + ch * 8;
    u16x8 o;
    if (bf) {
        o = *(const u16x8*)((const u16*)embed + src);
    } else {
        const float* ef = (const float*)embed + src;
        f32x4 lo = *(const f32x4*)ef;
        f32x4 hi = *(const f32x4*)(ef + 4);
        o[0]=f2b(lo[0]); o[1]=f2b(lo[1]); o[2]=f2b(lo[2]); o[3]=f2b(lo[3]);
        o[4]=f2b(hi[0]); o[5]=f2b(hi[1]); o[6]=f2b(hi[2]); o[7]=f2b(hi[3]);
    }
    *(u16x8*)(x0 + (long)m * CE + ch * 8) = o;
}

// ---- tiled bf16 MFMA GEMM: A[M,KD] @ B[1024,KD]^T + bias -> Z (t-major) ----
// BK=64 with XOR bank-swizzle (rule #21): LDS rows are 128 B, so unswizzled
// fragment reads are a 16-way bank conflict (all lr hit bank 0). Swizzle:
// 16B-slot_phys = slot_log ^ (row&7), applied by permuting the GLOBAL source
// (gload_lds dest stays linear) and the ds_read column. LDS stage aliased
// with epilogue cho, XCD-swizzled grid, bias folded, t-major Z slabs.
template<int KD>
__global__ __launch_bounds__(256) void gemm_k(const u16* __restrict__ A,
                                              const u16* __restrict__ Bw,
                                              const float* __restrict__ bias,
                                              u16* __restrict__ Zp)
{
    const int bid = (blockIdx.x & 7) * 512 + (blockIdx.x >> 3);   // XCD swizzle (4096%8==0)
    const int bm = bid >> 3, bn = bid & 7;
    const long m0 = (long)bm * 128;
    const int n0 = bn * 128;
    const int tid = threadIdx.x, lane = tid & 63, wave = tid >> 6;
    const int wm = wave >> 1, wn = wave & 1;
    const int lr = lane & 15, kg = (lane >> 4) * 8;

    __shared__ __align__(16) char smem[34816];     // stage (32KB) aliased w/ cho (34.8KB)
    __shared__ float bsm[128];
    u16 (*At)[64] = (u16(*)[64])smem;              // [128][64]
    u16 (*Bt)[64] = (u16(*)[64])(smem + 16384);    // [128][64]
    u16 (*cho)[136] = (u16(*)[136])smem;           // [128][136] (epilogue only)
    if (tid < 128) bsm[tid] = bias[n0 + tid];

    f32x4 acc[4][4];
    #pragma unroll
    for (int i = 0; i < 4; ++i)
        #pragma unroll
        for (int j = 0; j < 4; ++j) acc[i][j] = (f32x4){0.f, 0.f, 0.f, 0.f};

    // staging: physical LDS byte = tid*16 (+r*4096). row = tid>>3, slot_phys =
    // tid&7. Source col carries the data for slot_log = slot_phys ^ (row&7).
    const int srow = tid >> 3;
    const int scol = (((tid & 7) ^ ((tid >> 3) & 7)) * 8);
    char* db = smem + (tid & ~63) * 16;            // wave-uniform dest base (wave*1024)
    for (int kk = 0; kk < KD; kk += 64) {
        __syncthreads();                        // previous-iter reads done
        #pragma unroll
        for (int r = 0; r < 4; ++r)
            gload_lds16(A + (m0 + srow + r * 32) * KD + kk + scol, db + r * 4096);
        #pragma unroll
        for (int r = 0; r < 4; ++r)
            gload_lds16(Bw + (long)(n0 + srow + r * 32) * KD + kk + scol,
                        db + 16384 + r * 4096);
        __syncthreads();                        // vmcnt drained -> tile ready
        #pragma unroll
        for (int kh = 0; kh < 64; kh += 32) {
            bf16x8 af[4], bfv[4];
            #pragma unroll
            for (int mt = 0; mt < 4; ++mt) {
                const int slot = (((kh + kg) >> 3) ^ (lr & 7)) * 8;   // swizzled read
                af[mt] = *(const bf16x8*)&At[wm * 64 + mt * 16 + lr][slot];
            }
            #pragma unroll
            for (int nt = 0; nt < 4; ++nt) {
                const int slot = (((kh + kg) >> 3) ^ (lr & 7)) * 8;
                bfv[nt] = *(const bf16x8*)&Bt[wn * 64 + nt * 16 + lr][slot];
            }
            #pragma unroll
            for (int mt = 0; mt < 4; ++mt)
                #pragma unroll
                for (int nt = 0; nt < 4; ++nt)
                    acc[mt][nt] = __builtin_amdgcn_mfma_f32_16x16x32_bf16(
                        af[mt], bfv[nt], acc[mt][nt], 0, 0, 0);
        }
    }

    // C layout: col = lane&15, row = (lane>>4)*4 + r  [m89/m91-verified]
    __syncthreads();                            // last MFMA reads done; cho may alias
    const int rr0 = (lane >> 4) * 4;
    #pragma unroll
    for (int mt = 0; mt < 4; ++mt)
        #pragma unroll
        for (int nt = 0; nt < 4; ++nt) {
            const int colw = wn * 64 + nt * 16 + lr;            // r in gt block
            const int pc = (colw >> 5) * 32 + ((colw & 15) << 1) + ((colw >> 4) & 1);
            const float bv = bsm[colw];
            #pragma unroll
            for (int r = 0; r < 4; ++r)
                cho[wm * 64 + mt * 16 + rr0 + r][pc] = f2b(acc[mt][nt][r] + bv);
        }
    __syncthreads();
    // coalesced copy-out into the t-major slab
    const int brow = tid >> 1, hf = tid & 1;
    const int dd = n0 >> 9, gt = (n0 >> 7) & 3;
    const int t = bm;
    const int sz = dd ? (CT - 1 - t) : t;                      // scan-order slab
    u16* dst = Zp + ((long)sz * 256 + (brow * 2 + dd)) * 512 + gt * 128 + hf * 64;
    const u16* srcl = &cho[brow][hf * 64];
    #pragma unroll
    for (int p = 0; p < 8; ++p)
        *(u16x8*)(dst + p * 8) = *(const u16x8*)(srcl + p * 8);
}

// ---- LSTM scan v9 (R13 structure; t-major Z addressing): MX-fp8 K=128 MFMA ----
__global__ __launch_bounds__(256, 1) void scan_k(const u16* __restrict__ Zp,
                                                 const unsigned char* __restrict__ Whh8,
                                                 u16* __restrict__ hout)
{
    const int b = blockIdx.x & 127, d = blockIdx.x >> 7;
    const int tid = threadIdx.x;
    const int lane = tid & 63;
    const int wave = tid >> 6;                  // 0..3
    const int lr = lane & 15;
    const int kb8 = (lane >> 4) * 32;           // k-block byte offset (32 fp8)
    const int uhalf = (lane >> 4) & 1;          // 0: rows r0, 1: rows r0+16
    const int rowm = wave * 32 + (lane & 31);   // row finalized by this lane (lane<32)

    i32x8 bfrag[4][2];
    #pragma unroll
    for (int gt = 0; gt < 4; ++gt)
        #pragma unroll
        for (int uu = 0; uu < 2; ++uu) {
            const unsigned char* wb = Whh8 +
                ((long)(d * 512 + gt * 128 + wave * 32 + uu * 16 + lr) << 7) + kb8;
            const i32x4 lo = *(const i32x4*)wb;
            const i32x4 hi = *(const i32x4*)(wb + 16);
            bfrag[gt][uu] = (i32x8){lo[0], lo[1], lo[2], lo[3], hi[0], hi[1], hi[2], hi[3]};
        }

    __shared__ __align__(16) unsigned char hbuf8[2 * 128];   // fp8 h, double-buffered

    constexpr long SLAB = 256 * 256;            // u32 words per scan step (256 seq x 1KB)
    const u32* zw0 = (const u32*)Zp + (long)(b * 2 + d) * 256 + wave * 16 + lr;

    u32 zR[16][4];
    #pragma unroll
    for (int s = 0; s < 16; ++s) {
        #pragma unroll
        for (int g = 0; g < 4; ++g)
            zR[s][g] = zw0[(long)s * SLAB + g * 64];
    }
    const u32* znext = zw0 + 16 * SLAB;

    if (tid < 128) { hbuf8[tid] = 0; hbuf8[128 + tid] = 0; }
    asm volatile("s_waitcnt lgkmcnt(0)\n\ts_barrier" ::: "memory");

    float cst = 0.f;
    u16* hp = hout + ((long)(d ? (CT - 1) : 0) * CB + b) * 256 + d * 128 + rowm;
    const long hstep = (long)(d ? -1 : 1) * (CB * 256);

    for (int grp = 0; grp < 32; ++grp) {
        const bool more = grp < 31;
        #pragma unroll
        for (int slot = 0; slot < 16; ++slot) {
            const u32 zl0 = zR[slot][0], zl1 = zR[slot][1];
            const u32 zl2 = zR[slot][2], zl3 = zR[slot][3];
            if (more) {
                const u32* zp = znext + (long)slot * SLAB;
                zR[slot][0] = zp[0];
                zR[slot][1] = zp[64];
                zR[slot][2] = zp[128];
                zR[slot][3] = zp[192];
            }

            const unsigned char* hbp = hbuf8 + (slot & 1) * 128 + kb8;
            const i32x4 hlo = *(const i32x4*)hbp;
            const i32x4 hhi = *(const i32x4*)(hbp + 16);
            const i32x8 av = (i32x8){hlo[0], hlo[1], hlo[2], hlo[3],
                                     hhi[0], hhi[1], hhi[2], hhi[3]};

            f32x4 acc[4][2];
            #pragma unroll
            for (int gt = 0; gt < 4; ++gt) {
                acc[gt][0] = (f32x4){0.f, 0.f, 0.f, 0.f};
                acc[gt][1] = (f32x4){0.f, 0.f, 0.f, 0.f};
            }
            #pragma unroll
            for (int gt = 0; gt < 4; ++gt) {
                acc[gt][0] = __builtin_amdgcn_mfma_scale_f32_16x16x128_f8f6f4(
                    av, bfrag[gt][0], acc[gt][0], 0, 0,
                    0, 0x7F7F7F7F, 0, 0x7F7F7F7F);
                acc[gt][1] = __builtin_amdgcn_mfma_scale_f32_16x16x128_f8f6f4(
                    av, bfrag[gt][1], acc[gt][1], 0, 0,
                    0, 0x7F7F7F7F, 0, 0x7F7F7F7F);
            }

            const u32 zlw[4] = {zl0, zl1, zl2, zl3};
            float pg[4];
            #pragma unroll
            for (int gt = 0; gt < 4; ++gt) {
                union { u32 i; float f; } zz;
                zz.i = uhalf ? (zlw[gt] & 0xFFFF0000u) : (zlw[gt] << 16);
                const float sv = uhalf ? acc[gt][1][0] : acc[gt][0][0];
                pg[gt] = fmaf(sv, 0.125f, zz.f);    // undo the x8 weight scale
            }
            const float iv = sigm(pg[0]);
            const float fv = sigm(pg[1]);
            const float gg = tanh_f(pg[2]);
            const float ov = sigm(pg[3]);
            cst = fmaf(fv, cst, iv * gg);
            const float h = ov * tanh_f(cst);

            if (lane < 32) {
                const u32 pk = __builtin_amdgcn_cvt_pk_fp8_f32(h, h, 0, false);
                hbuf8[((slot + 1) & 1) * 128 + rowm] = (unsigned char)(pk & 0xFF);
                *hp = f2b(h);                        // bf16 for next layer / emis
            }
            hp += hstep;
            asm volatile("s_waitcnt lgkmcnt(0)\n\ts_barrier" ::: "memory");
        }
        znext += 16 * SLAB;
    }
}

// ---- emissions: em[m][20] = h1[m] @ Wout^T + bout (f32) ----
__global__ __launch_bounds__(256) void emis_k(const u16* __restrict__ h1,
                                              const u16* __restrict__ woutb,
                                              const float* __restrict__ boutf,
                                              float* __restrict__ em)
{
    __shared__ __align__(16) float wsm[CK * 256];
    for (int i = threadIdx.x; i < CK * 256; i += 256) wsm[i] = b2f(woutb[i]);
    __syncthreads();
    const long m = (long)blockIdx.x * 256 + threadIdx.x;
    const u16* hrow = h1 + m * 256;
    float acc[CK];
    #pragma unroll
    for (int n = 0; n < CK; ++n) acc[n] = boutf[n];
    for (int k8 = 0; k8 < 32; ++k8) {
        u16x8 u = *(const u16x8*)(hrow + k8 * 8);
        float hv[8];
        #pragma unroll
        for (int j = 0; j < 8; ++j) hv[j] = b2f(u[j]);
        #pragma unroll
        for (int n = 0; n < CK; ++n) {
            const f32x4 w0 = *(const f32x4*)&wsm[n * 256 + k8 * 8];
            const f32x4 w1 = *(const f32x4*)&wsm[n * 256 + k8 * 8 + 4];
            acc[n] = fmaf(hv[0], w0[0], acc[n]); acc[n] = fmaf(hv[1], w0[1], acc[n]);
            acc[n] = fmaf(hv[2], w0[2], acc[n]); acc[n] = fmaf(hv[3], w0[3], acc[n]);
            acc[n] = fmaf(hv[4], w1[0], acc[n]); acc[n] = fmaf(hv[5], w1[1], acc[n]);
            acc[n] = fmaf(hv[6], w1[2], acc[n]); acc[n] = fmaf(hv[7], w1[3], acc[n]);
        }
    }
    float* emrow = em + m * CK;
    #pragma unroll
    for (int n = 0; n < CK; ++n) emrow[n] = acc[n];
}

// ---- CRF (exp-space denominator, R12) ----
__global__ void crf_k(const float* __restrict__ em, const int* __restrict__ tags,
                      const float* __restrict__ trf, const float* __restrict__ stf,
                      const float* __restrict__ enf, float* __restrict__ partial)
{
    const int lane = threadIdx.x;      // 64
    if (blockIdx.x < 64) {
        const int j = lane & 31, half = lane >> 5;
        const int b = blockIdx.x * 2 + half;
        const bool act = j < CK;
        float tcol[CK];                          // exp(trans[i][j])
        #pragma unroll
        for (int i = 0; i < CK; ++i) tcol[i] = act ? __expf(trf[i * CK + j]) : 0.f;
        float p = act ? __expf(stf[j] + em[(long)b * CK + j]) : 0.f;
        float L = 0.f;
        float emn = act ? em[((long)1 * CB + b) * CK + j] : 0.f;  // prefetch t=1
        for (int t = 1; t < CT; ++t) {
            const float emv = emn;
            if (t + 1 < CT)
                emn = act ? em[((long)(t + 1) * CB + b) * CK + j] : 0.f;
            float pi[CK];
            #pragma unroll
            for (int i = 0; i < CK; ++i) pi[i] = __shfl(p, i, 32);
            float a0 = 0.f, a1 = 0.f, a2 = 0.f, a3 = 0.f;
            #pragma unroll
            for (int i = 0; i < CK; i += 4) {
                a0 = fmaf(pi[i], tcol[i], a0);
                a1 = fmaf(pi[i + 1], tcol[i + 1], a1);
                a2 = fmaf(pi[i + 2], tcol[i + 2], a2);
                a3 = fmaf(pi[i + 3], tcol[i + 3], a3);
            }
            p = ((a0 + a1) + (a2 + a3)) * __expf(emv);
            if ((t & 7) == 0) {                  // renorm
                float sum = act ? p : 0.f;
                #pragma unroll
                for (int off = 16; off; off >>= 1) sum += __shfl_xor(sum, off, 32);
                L += __logf(sum);
                p *= (1.0f / sum);
            }
        }
        float vv = act ? (__logf(p) + L + enf[j]) : -1e30f;
        float mx = vv;
        #pragma unroll
        for (int off = 16; off; off >>= 1) mx = fmaxf(mx, __shfl_xor(mx, off, 32));
        float ex = act ? __expf(vv - mx) : 0.f;
        #pragma unroll
        for (int off = 16; off; off >>= 1) ex += __shfl_xor(ex, off, 32);
        if (j == 0) partial[b] = mx + __logf(ex);
    } else {
        const int b = blockIdx.x - 64;
        float sc = 0.f;
        for (int t = lane; t < CT; t += 64) {
            const int tg = tags[b * CT + t];
            sc += em[((long)t * CB + b) * CK + tg];
            if (t >= 1) sc += trf[tags[b * CT + t - 1] * CK + tg];
        }
        #pragma unroll
        for (int off = 32; off; off >>= 1) sc += __shfl_xor(sc, off);
        if (lane == 0)
            partial[128 + b] = sc + stf[tags[b * CT]] + enf[tags[b * CT + CT - 1]];
    }
}

__global__ void fin_k(const float* __restrict__ partial, void* __restrict__ out,
                      const unsigned char* __restrict__ ws)
{
    const int bf = *(const int*)(ws + OFF_FLAG);
    const int lane = threadIdx.x;  // 64
    float v = (partial[lane] - partial[128 + lane]) + (partial[lane + 64] - partial[192 + lane]);
    #pragma unroll
    for (int off = 32; off; off >>= 1) v += __shfl_xor(v, off);
    if (lane == 0) {
        const float mean = v / 128.f;
        if (bf) ((u16*)out)[0] = f2b(mean);
        else    ((float*)out)[0] = mean;
    }
}

extern "C" void kernel_launch(void* const* d_in, const int* in_sizes, int n_in,
                              void* d_out, int out_size, void* d_ws, size_t ws_size,
                              hipStream_t stream) {
    (void)in_sizes; (void)n_in; (void)out_size;
    if (ws_size < WS_NEED) return;
    unsigned char* ws = (unsigned char*)d_ws;

    const void* sent  = d_in[0];
    const void* tags  = d_in[1];
    const void* embed = d_in[3];

    u16* x0  = (u16*)(ws + OFF_X0);
    u16* h0  = (u16*)(ws + OFF_H0);
    u16* h1  = (u16*)(ws + OFF_H1);
    u16* Zb  = (u16*)(ws + OFF_Z);
    float* em = (float*)(ws + OFF_EM);
    float* part = (float*)(ws + OFF_PART);

    sniff_k<<<1, 64, 0, stream>>>((const unsigned char*)d_in[12], (int*)(ws + OFF_FLAG));
    prep_k<<<3102, 256, 0, stream>>>(d_in[4], d_in[5], d_in[6], d_in[7], d_in[8],
                                     d_in[9], d_in[10], d_in[11], d_in[12], d_in[13],
                                     d_in[14], ws);
    gather_k<<<4096, 256, 0, stream>>>(embed, (const int*)sent, ws);
    // layer 0
    gemm_k<128><<<4096, 256, 0, stream>>>(x0, (const u16*)(ws + OFF_WIH0),
                                          (const float*)(ws + OFF_B0), Zb);
    scan_k<<<256, 256, 0, stream>>>(Zb, (const unsigned char*)(ws + OFF_WHH0F8), h0);
    // layer 1
    gemm_k<256><<<4096, 256, 0, stream>>>(h0, (const u16*)(ws + OFF_WIH1),
                                          (const float*)(ws + OFF_B1), Zb);
    scan_k<<<256, 256, 0, stream>>>(Zb, (const unsigned char*)(ws + OFF_WHH1F8), h1);
    // emissions + CRF
    emis_k<<<256, 256, 0, stream>>>(h1, (const u16*)(ws + OFF_WOUT),
                                    (const float*)(ws + OFF_BOUT), em);
    crf_k<<<192, 64, 0, stream>>>(em, (const int*)tags,
                                  (const float*)(ws + OFF_TRANS),
                                  (const float*)(ws + OFF_START),
                                  (const float*)(ws + OFF_END), part);
    fin_k<<<1, 64, 0, stream>>>(part, d_out, ws);
}

// Round 18
// 858.734 us; speedup vs baseline: 1.0070x; 1.0070x over previous
//
#include <hip/hip_runtime.h>
#include <hip/hip_bf16.h>
#include <cstddef>

typedef unsigned short u16;
typedef unsigned int u32;
typedef short bf16x8 __attribute__((ext_vector_type(8)));
typedef unsigned short u16x8 __attribute__((ext_vector_type(8)));
typedef float f32x4 __attribute__((ext_vector_type(4)));
typedef int i32x4 __attribute__((ext_vector_type(4)));
typedef int i32x8 __attribute__((ext_vector_type(8)));

constexpr int CB = 128;    // batch
constexpr int CT = 512;    // time
constexpr int CE = 128;    // embed dim
constexpr int CK = 20;     // tags

// ---- workspace layout (bytes) ----
constexpr size_t OFF_FLAG   = 0;                      // int dtype flag (1=bf16 inputs)
constexpr size_t OFF_WIH0   = 256;                    // bf16 [1024][128]
constexpr size_t OFF_WHH0   = OFF_WIH0 + 262144;      // bf16 [1024][128]
constexpr size_t OFF_WIH1   = OFF_WHH0 + 262144;      // bf16 [1024][256]
constexpr size_t OFF_WHH1   = OFF_WIH1 + 524288;      // bf16 [1024][128]
constexpr size_t OFF_WOUT   = OFF_WHH1 + 262144;      // bf16 [20][256]
constexpr size_t OFF_B0     = OFF_WOUT + 10240;       // f32 [1024]
constexpr size_t OFF_B1     = OFF_B0 + 4096;          // f32 [1024]
constexpr size_t OFF_BOUT   = OFF_B1 + 4096;          // f32 [20]
constexpr size_t OFF_TRANS  = OFF_BOUT + 256;         // f32 [400]
constexpr size_t OFF_START  = OFF_TRANS + 1792;       // f32 [20]
constexpr size_t OFF_END    = OFF_START + 256;        // f32 [20]
constexpr size_t OFF_PART   = OFF_END + 256;          // f32 [256]: logZ[128], score[128]
constexpr size_t OFF_WHH0F8 = OFF_PART + 256;         // fp8 e4m3 (x8-scaled) [1024][128]
constexpr size_t OFF_WHH1F8 = OFF_WHH0F8 + 131072;    // fp8 e4m3 (x8-scaled) [1024][128]
constexpr size_t OFF_X0     = 2097152;                // bf16 [65536][128]
constexpr size_t OFF_H0     = OFF_X0 + 16777216;      // bf16 [65536][256]
constexpr size_t OFF_H1     = OFF_H0 + 33554432;      // bf16 [65536][256]
constexpr size_t OFF_EM     = OFF_H1 + 33554432;      // f32  [65536][20]
constexpr size_t OFF_Z      = OFF_EM + 5242880;       // bf16 Z[t_scan][seq=b*2+d][512] t-major, bias-folded
constexpr size_t WS_NEED    = OFF_Z + 134217728;      // ~225.4 MB

__device__ __forceinline__ float b2f(u16 u) {
    union { u32 i; float f; } v; v.i = ((u32)u) << 16; return v.f;
}
__device__ __forceinline__ u16 f2b(float f) {
    union { float f; u32 i; } v; v.f = f;
    u32 r = v.i + 0x7FFFu + ((v.i >> 16) & 1u);   // RNE
    return (u16)(r >> 16);
}
__device__ __forceinline__ float ldin(const void* p, long i, int bf) {
    return bf ? b2f(((const u16*)p)[i]) : ((const float*)p)[i];
}
__device__ __forceinline__ float sigm(float x) { return 1.0f / (1.0f + __expf(-x)); }
__device__ __forceinline__ float tanh_f(float x) { return 2.0f / (1.0f + __expf(-2.0f * x)) - 1.0f; }

// async global -> LDS, 16 B per lane. dest must be wave-uniform base (HW adds lane*16).
__device__ __forceinline__ void gload_lds16(const void* g, void* l) {
    __builtin_amdgcn_global_load_lds(
        (const __attribute__((address_space(1))) void*)g,
        (__attribute__((address_space(3))) void*)l, 16, 0, 0);
}

// ---- detect whether float inputs are bf16 or f32, from `trans` ----
__global__ void sniff_k(const unsigned char* __restrict__ traw, int* __restrict__ flag) {
    int lane = threadIdx.x;
    int votes = 0;
    for (int w = lane; w < 200; w += 64) {
        unsigned char b1 = traw[w * 4 + 1];
        unsigned char e = b1 & 0x7F;
        if (e >= 0x20 && e <= 0x3E) votes++;
    }
    #pragma unroll
    for (int off = 32; off; off >>= 1) votes += __shfl_xor(votes, off);
    if (lane == 0) *flag = (votes > 120) ? 1 : 0;
}

// ---- convert all weights into canonical ws copies ----
__global__ __launch_bounds__(256) void prep_k(
    const void* wih0, const void* whh0, const void* b0,
    const void* wih1, const void* whh1, const void* b1,
    const void* wout, const void* bout, const void* trans,
    const void* start, const void* end, unsigned char* ws)
{
    const int bf = *(const int*)(ws + OFF_FLAG);
    long tid = (long)blockIdx.x * 256 + threadIdx.x;
    u16* wih0b = (u16*)(ws + OFF_WIH0);
    u16* whh0b = (u16*)(ws + OFF_WHH0);
    u16* wih1b = (u16*)(ws + OFF_WIH1);
    u16* whh1b = (u16*)(ws + OFF_WHH1);
    u16* woutb = (u16*)(ws + OFF_WOUT);
    float* b0f   = (float*)(ws + OFF_B0);
    float* b1f   = (float*)(ws + OFF_B1);
    float* boutf = (float*)(ws + OFF_BOUT);
    float* trf   = (float*)(ws + OFF_TRANS);
    float* stf   = (float*)(ws + OFF_START);
    float* enf   = (float*)(ws + OFF_END);

    if (tid < 131072) { wih0b[tid] = f2b(ldin(wih0, tid, bf)); return; } tid -= 131072;
    if (tid < 131072) { whh0b[tid] = f2b(ldin(whh0, tid, bf)); return; } tid -= 131072;
    if (tid < 1024)   { b0f[tid]   = ldin(b0, tid, bf);        return; } tid -= 1024;
    if (tid < 262144) { wih1b[tid] = f2b(ldin(wih1, tid, bf)); return; } tid -= 262144;
    if (tid < 131072) { whh1b[tid] = f2b(ldin(whh1, tid, bf)); return; } tid -= 131072;
    if (tid < 1024)   { b1f[tid]   = ldin(b1, tid, bf);        return; } tid -= 1024;
    if (tid < 5120)   { woutb[tid] = f2b(ldin(wout, tid, bf)); return; } tid -= 5120;
    if (tid < 20)     { boutf[tid] = ldin(bout, tid, bf);      return; } tid -= 20;
    if (tid < 400)    { trf[tid]   = ldin(trans, tid, bf);     return; } tid -= 400;
    if (tid < 20)     { stf[tid]   = ldin(start, tid, bf);     return; } tid -= 20;
    if (tid < 20)     { enf[tid]   = ldin(end, tid, bf);       return; } tid -= 20;
    // fp8 e4m3 (x8-scaled) copies of Whh for the scan's MX MFMA
    if (tid < 65536) {
        const float v0 = ldin(whh0, tid * 2, bf) * 8.0f;
        const float v1 = ldin(whh0, tid * 2 + 1, bf) * 8.0f;
        const u32 pk = __builtin_amdgcn_cvt_pk_fp8_f32(v0, v1, 0, false);
        ((u16*)(ws + OFF_WHH0F8))[tid] = (u16)(pk & 0xFFFF);
        return;
    } tid -= 65536;
    if (tid < 65536) {
        const float v0 = ldin(whh1, tid * 2, bf) * 8.0f;
        const float v1 = ldin(whh1, tid * 2 + 1, bf) * 8.0f;
        const u32 pk = __builtin_amdgcn_cvt_pk_fp8_f32(v0, v1, 0, false);
        ((u16*)(ws + OFF_WHH1F8))[tid] = (u16)(pk & 0xFFFF);
        return;
    }
}

// ---- embedding gather -> x0 bf16 [m = t*CB+b][128] ----
__global__ __launch_bounds__(256) void gather_k(const void* __restrict__ embed,
                                                const int* __restrict__ sent,
                                                unsigned char* __restrict__ ws)
{
    const int bf = *(const int*)(ws + OFF_FLAG);
    u16* x0 = (u16*)(ws + OFF_X0);
    int tid = blockIdx.x * 256 + threadIdx.x;      // 1,048,576 threads
    int m = tid >> 4, ch = tid & 15;
    int t = m >> 7, b = m & 127;
    int s = sent[b * CT + t];
    long src = (long)s * CE + ch * 8;
    u16x8 o;
    if (bf) {
        o = *(const u16x8*)((const u16*)embed + src);
    } else {
        const float* ef = (const float*)embed + src;
        f32x4 lo = *(const f32x4*)ef;
        f32x4 hi = *(const f32x4*)(ef + 4);
        o[0]=f2b(lo[0]); o[1]=f2b(lo[1]); o[2]=f2b(lo[2]); o[3]=f2b(lo[3]);
        o[4]=f2b(hi[0]); o[5]=f2b(hi[1]); o[6]=f2b(hi[2]); o[7]=f2b(hi[3]);
    }
    *(u16x8*)(x0 + (long)m * CE + ch * 8) = o;
}

// ---- B-resident bf16 MFMA GEMM: A[65536,KD] @ B[1024,KD]^T + bias -> Z (t-major) ----
// grid = 8 bn x 32 mg = 256 blocks (1/CU), blockIdx = bn*32 + mg so the 8
// bn-blocks sharing an A-panel land on one XCD (bid%8 == mg%8): A hits L2
// after the first of the 8. B-panel [128][KD] staged in LDS ONCE; 16 A-tiles
// of 128 rows x full K each (one stage per 512 block-MFMAs vs 4 drain pairs
// in the old BK-loop). A prefetched into registers during the MFMA phase
// (T14) and committed to LDS after the epilogue. XOR slot swizzle on both
// sides. Bias folded; Z written t-major with the pc permutation (as R16/17).
template<int KD>
__global__ __launch_bounds__(256, 1) void gemm_k(const u16* __restrict__ A,
                                                 const u16* __restrict__ Bw,
                                                 const float* __restrict__ bias,
                                                 u16* __restrict__ Zp)
{
    constexpr int TB = 128 * KD * 2;               // tile bytes (A or B panel)
    constexpr int NI = TB / 4096;                  // stage instrs (per 4KB block-chunk)
    constexpr int AR = (TB > 34816) ? TB : 34816;  // A region >= cho (aliased)
    const int bn = blockIdx.x >> 5, mg = blockIdx.x & 31;
    const int n0 = bn * 128;
    const int tid = threadIdx.x, lane = tid & 63, wave = tid >> 6;
    const int wm = wave >> 1, wn = wave & 1;
    const int lr = lane & 15, kg = (lane >> 4) * 8;

    __shared__ __align__(16) char smem[AR + TB];
    __shared__ float bsm[128];
    u16 (*At)[KD] = (u16(*)[KD])smem;
    u16 (*Bt)[KD] = (u16(*)[KD])(smem + AR);
    u16 (*cho)[136] = (u16(*)[136])smem;           // epilogue alias of A region
    if (tid < 128) bsm[tid] = bias[n0 + tid];

    // swizzled per-lane source offset (u16 elems) for linear LDS byte p:
    //   row = p/(2KD), slot_phys = (p/16)%(KD/8), slot_log = slot_phys^(row&7)
    auto swsrc = [&](int p) -> long {
        const int row = p / (2 * KD);
        const int sp = (p >> 4) & (KD / 8 - 1);
        const int sl = sp ^ (row & 7);
        return (long)row * KD + sl * 8;
    };

    // prologue: stage B panel (contiguous at Bw + n0*KD) and A tile 0
    char* db = smem + (tid & ~63) * 16;            // wave-uniform dest base
    const u16* Bsrc = Bw + (long)n0 * KD;
    const u16* Asrc = A + (long)(mg) * 128 * KD;   // tile it=0: m0 = mg*128
    #pragma unroll
    for (int i = 0; i < NI; ++i)
        gload_lds16(Bsrc + swsrc(i * 4096 + tid * 16), db + AR + i * 4096);
    #pragma unroll
    for (int i = 0; i < NI; ++i)
        gload_lds16(Asrc + swsrc(i * 4096 + tid * 16), db + i * 4096);
    __syncthreads();                               // panels ready

    u16x8 areg[NI];
    for (int it = 0; it < 16; ++it) {
        const int tile = mg + 32 * it;             // = t (A row m = t*CB + b)
        // issue next tile's loads (ride under the MFMA phase)
        if (it + 1 < 16) {
            const u16* An = A + (long)(mg + 32 * (it + 1)) * 128 * KD;
            #pragma unroll
            for (int i = 0; i < NI; ++i)
                areg[i] = *(const u16x8*)(An + swsrc(i * 4096 + tid * 16));
        }

        f32x4 acc[4][4];
        #pragma unroll
        for (int i = 0; i < 4; ++i)
            #pragma unroll
            for (int j = 0; j < 4; ++j) acc[i][j] = (f32x4){0.f, 0.f, 0.f, 0.f};

        #pragma unroll
        for (int kt = 0; kt < KD / 32; ++kt) {
            const int slot = (((kt * 32 + kg) >> 3) ^ (lr & 7)) * 8;
            bf16x8 af[4], bfv[4];
            #pragma unroll
            for (int mt = 0; mt < 4; ++mt)
                af[mt] = *(const bf16x8*)&At[wm * 64 + mt * 16 + lr][slot];
            #pragma unroll
            for (int nt = 0; nt < 4; ++nt)
                bfv[nt] = *(const bf16x8*)&Bt[wn * 64 + nt * 16 + lr][slot];
            #pragma unroll
            for (int mt = 0; mt < 4; ++mt)
                #pragma unroll
                for (int nt = 0; nt < 4; ++nt)
                    acc[mt][nt] = __builtin_amdgcn_mfma_f32_16x16x32_bf16(
                        af[mt], bfv[nt], acc[mt][nt], 0, 0, 0);
        }

        // epilogue: C layout col=lane&15, row=(lane>>4)*4+r  [m89/m91-verified]
        __syncthreads();                           // MFMA LDS reads done; cho aliases At
        const int rr0 = (lane >> 4) * 4;
        #pragma unroll
        for (int mt = 0; mt < 4; ++mt)
            #pragma unroll
            for (int nt = 0; nt < 4; ++nt) {
                const int colw = wn * 64 + nt * 16 + lr;
                const int pc = (colw >> 5) * 32 + ((colw & 15) << 1) + ((colw >> 4) & 1);
                const float bv = bsm[colw];
                #pragma unroll
                for (int r = 0; r < 4; ++r)
                    cho[wm * 64 + mt * 16 + rr0 + r][pc] = f2b(acc[mt][nt][r] + bv);
            }
        __syncthreads();
        // coalesced copy-out into the t-major slab
        const int brow = tid >> 1, hf = tid & 1;
        const int dd = n0 >> 9, gt = (n0 >> 7) & 3;
        const int sz = dd ? (CT - 1 - tile) : tile;
        u16* dst = Zp + ((long)sz * 256 + (brow * 2 + dd)) * 512 + gt * 128 + hf * 64;
        const u16* srcl = &cho[brow][hf * 64];
        #pragma unroll
        for (int p = 0; p < 8; ++p)
            *(u16x8*)(dst + p * 8) = *(const u16x8*)(srcl + p * 8);
        __syncthreads();                           // cho reads done; A region free
        if (it + 1 < 16) {
            #pragma unroll
            for (int i = 0; i < NI; ++i)
                *(u16x8*)(smem + i * 4096 + tid * 16) = areg[i];
            __syncthreads();                       // next A published
        }
    }
}

// ---- LSTM scan v9 (R13 structure; t-major Z addressing): MX-fp8 K=128 MFMA ----
__global__ __launch_bounds__(256, 1) void scan_k(const u16* __restrict__ Zp,
                                                 const unsigned char* __restrict__ Whh8,
                                                 u16* __restrict__ hout)
{
    const int b = blockIdx.x & 127, d = blockIdx.x >> 7;
    const int tid = threadIdx.x;
    const int lane = tid & 63;
    const int wave = tid >> 6;                  // 0..3
    const int lr = lane & 15;
    const int kb8 = (lane >> 4) * 32;           // k-block byte offset (32 fp8)
    const int uhalf = (lane >> 4) & 1;          // 0: rows r0, 1: rows r0+16
    const int rowm = wave * 32 + (lane & 31);   // row finalized by this lane (lane<32)

    i32x8 bfrag[4][2];
    #pragma unroll
    for (int gt = 0; gt < 4; ++gt)
        #pragma unroll
        for (int uu = 0; uu < 2; ++uu) {
            const unsigned char* wb = Whh8 +
                ((long)(d * 512 + gt * 128 + wave * 32 + uu * 16 + lr) << 7) + kb8;
            const i32x4 lo = *(const i32x4*)wb;
            const i32x4 hi = *(const i32x4*)(wb + 16);
            bfrag[gt][uu] = (i32x8){lo[0], lo[1], lo[2], lo[3], hi[0], hi[1], hi[2], hi[3]};
        }

    __shared__ __align__(16) unsigned char hbuf8[2 * 128];   // fp8 h, double-buffered

    constexpr long SLAB = 256 * 256;            // u32 words per scan step (256 seq x 1KB)
    const u32* zw0 = (const u32*)Zp + (long)(b * 2 + d) * 256 + wave * 16 + lr;

    u32 zR[16][4];
    #pragma unroll
    for (int s = 0; s < 16; ++s) {
        #pragma unroll
        for (int g = 0; g < 4; ++g)
            zR[s][g] = zw0[(long)s * SLAB + g * 64];
    }
    const u32* znext = zw0 + 16 * SLAB;

    if (tid < 128) { hbuf8[tid] = 0; hbuf8[128 + tid] = 0; }
    asm volatile("s_waitcnt lgkmcnt(0)\n\ts_barrier" ::: "memory");

    float cst = 0.f;
    u16* hp = hout + ((long)(d ? (CT - 1) : 0) * CB + b) * 256 + d * 128 + rowm;
    const long hstep = (long)(d ? -1 : 1) * (CB * 256);

    for (int grp = 0; grp < 32; ++grp) {
        const bool more = grp < 31;
        #pragma unroll
        for (int slot = 0; slot < 16; ++slot) {
            const u32 zl0 = zR[slot][0], zl1 = zR[slot][1];
            const u32 zl2 = zR[slot][2], zl3 = zR[slot][3];
            if (more) {
                const u32* zp = znext + (long)slot * SLAB;
                zR[slot][0] = zp[0];
                zR[slot][1] = zp[64];
                zR[slot][2] = zp[128];
                zR[slot][3] = zp[192];
            }

            const unsigned char* hbp = hbuf8 + (slot & 1) * 128 + kb8;
            const i32x4 hlo = *(const i32x4*)hbp;
            const i32x4 hhi = *(const i32x4*)(hbp + 16);
            const i32x8 av = (i32x8){hlo[0], hlo[1], hlo[2], hlo[3],
                                     hhi[0], hhi[1], hhi[2], hhi[3]};

            f32x4 acc[4][2];
            #pragma unroll
            for (int gt = 0; gt < 4; ++gt) {
                acc[gt][0] = (f32x4){0.f, 0.f, 0.f, 0.f};
                acc[gt][1] = (f32x4){0.f, 0.f, 0.f, 0.f};
            }
            #pragma unroll
            for (int gt = 0; gt < 4; ++gt) {
                acc[gt][0] = __builtin_amdgcn_mfma_scale_f32_16x16x128_f8f6f4(
                    av, bfrag[gt][0], acc[gt][0], 0, 0,
                    0, 0x7F7F7F7F, 0, 0x7F7F7F7F);
                acc[gt][1] = __builtin_amdgcn_mfma_scale_f32_16x16x128_f8f6f4(
                    av, bfrag[gt][1], acc[gt][1], 0, 0,
                    0, 0x7F7F7F7F, 0, 0x7F7F7F7F);
            }

            const u32 zlw[4] = {zl0, zl1, zl2, zl3};
            float pg[4];
            #pragma unroll
            for (int gt = 0; gt < 4; ++gt) {
                union { u32 i; float f; } zz;
                zz.i = uhalf ? (zlw[gt] & 0xFFFF0000u) : (zlw[gt] << 16);
                const float sv = uhalf ? acc[gt][1][0] : acc[gt][0][0];
                pg[gt] = fmaf(sv, 0.125f, zz.f);    // undo the x8 weight scale
            }
            const float iv = sigm(pg[0]);
            const float fv = sigm(pg[1]);
            const float gg = tanh_f(pg[2]);
            const float ov = sigm(pg[3]);
            cst = fmaf(fv, cst, iv * gg);
            const float h = ov * tanh_f(cst);

            if (lane < 32) {
                const u32 pk = __builtin_amdgcn_cvt_pk_fp8_f32(h, h, 0, false);
                hbuf8[((slot + 1) & 1) * 128 + rowm] = (unsigned char)(pk & 0xFF);
                *hp = f2b(h);                        // bf16 for next layer / emis
            }
            hp += hstep;
            asm volatile("s_waitcnt lgkmcnt(0)\n\ts_barrier" ::: "memory");
        }
        znext += 16 * SLAB;
    }
}

// ---- emissions: em[m][20] = h1[m] @ Wout^T + bout (f32) ----
__global__ __launch_bounds__(256) void emis_k(const u16* __restrict__ h1,
                                              const u16* __restrict__ woutb,
                                              const float* __restrict__ boutf,
                                              float* __restrict__ em)
{
    __shared__ __align__(16) float wsm[CK * 256];
    for (int i = threadIdx.x; i < CK * 256; i += 256) wsm[i] = b2f(woutb[i]);
    __syncthreads();
    const long m = (long)blockIdx.x * 256 + threadIdx.x;
    const u16* hrow = h1 + m * 256;
    float acc[CK];
    #pragma unroll
    for (int n = 0; n < CK; ++n) acc[n] = boutf[n];
    for (int k8 = 0; k8 < 32; ++k8) {
        u16x8 u = *(const u16x8*)(hrow + k8 * 8);
        float hv[8];
        #pragma unroll
        for (int j = 0; j < 8; ++j) hv[j] = b2f(u[j]);
        #pragma unroll
        for (int n = 0; n < CK; ++n) {
            const f32x4 w0 = *(const f32x4*)&wsm[n * 256 + k8 * 8];
            const f32x4 w1 = *(const f32x4*)&wsm[n * 256 + k8 * 8 + 4];
            acc[n] = fmaf(hv[0], w0[0], acc[n]); acc[n] = fmaf(hv[1], w0[1], acc[n]);
            acc[n] = fmaf(hv[2], w0[2], acc[n]); acc[n] = fmaf(hv[3], w0[3], acc[n]);
            acc[n] = fmaf(hv[4], w1[0], acc[n]); acc[n] = fmaf(hv[5], w1[1], acc[n]);
            acc[n] = fmaf(hv[6], w1[2], acc[n]); acc[n] = fmaf(hv[7], w1[3], acc[n]);
        }
    }
    float* emrow = em + m * CK;
    #pragma unroll
    for (int n = 0; n < CK; ++n) emrow[n] = acc[n];
}

// ---- CRF (exp-space denominator, R12) ----
__global__ void crf_k(const float* __restrict__ em, const int* __restrict__ tags,
                      const float* __restrict__ trf, const float* __restrict__ stf,
                      const float* __restrict__ enf, float* __restrict__ partial)
{
    const int lane = threadIdx.x;      // 64
    if (blockIdx.x < 64) {
        const int j = lane & 31, half = lane >> 5;
        const int b = blockIdx.x * 2 + half;
        const bool act = j < CK;
        float tcol[CK];                          // exp(trans[i][j])
        #pragma unroll
        for (int i = 0; i < CK; ++i) tcol[i] = act ? __expf(trf[i * CK + j]) : 0.f;
        float p = act ? __expf(stf[j] + em[(long)b * CK + j]) : 0.f;
        float L = 0.f;
        float emn = act ? em[((long)1 * CB + b) * CK + j] : 0.f;  // prefetch t=1
        for (int t = 1; t < CT; ++t) {
            const float emv = emn;
            if (t + 1 < CT)
                emn = act ? em[((long)(t + 1) * CB + b) * CK + j] : 0.f;
            float pi[CK];
            #pragma unroll
            for (int i = 0; i < CK; ++i) pi[i] = __shfl(p, i, 32);
            float a0 = 0.f, a1 = 0.f, a2 = 0.f, a3 = 0.f;
            #pragma unroll
            for (int i = 0; i < CK; i += 4) {
                a0 = fmaf(pi[i], tcol[i], a0);
                a1 = fmaf(pi[i + 1], tcol[i + 1], a1);
                a2 = fmaf(pi[i + 2], tcol[i + 2], a2);
                a3 = fmaf(pi[i + 3], tcol[i + 3], a3);
            }
            p = ((a0 + a1) + (a2 + a3)) * __expf(emv);
            if ((t & 7) == 0) {                  // renorm
                float sum = act ? p : 0.f;
                #pragma unroll
                for (int off = 16; off; off >>= 1) sum += __shfl_xor(sum, off, 32);
                L += __logf(sum);
                p *= (1.0f / sum);
            }
        }
        float vv = act ? (__logf(p) + L + enf[j]) : -1e30f;
        float mx = vv;
        #pragma unroll
        for (int off = 16; off; off >>= 1) mx = fmaxf(mx, __shfl_xor(mx, off, 32));
        float ex = act ? __expf(vv - mx) : 0.f;
        #pragma unroll
        for (int off = 16; off; off >>= 1) ex += __shfl_xor(ex, off, 32);
        if (j == 0) partial[b] = mx + __logf(ex);
    } else {
        const int b = blockIdx.x - 64;
        float sc = 0.f;
        for (int t = lane; t < CT; t += 64) {
            const int tg = tags[b * CT + t];
            sc += em[((long)t * CB + b) * CK + tg];
            if (t >= 1) sc += trf[tags[b * CT + t - 1] * CK + tg];
        }
        #pragma unroll
        for (int off = 32; off; off >>= 1) sc += __shfl_xor(sc, off);
        if (lane == 0)
            partial[128 + b] = sc + stf[tags[b * CT]] + enf[tags[b * CT + CT - 1]];
    }
}

__global__ void fin_k(const float* __restrict__ partial, void* __restrict__ out,
                      const unsigned char* __restrict__ ws)
{
    const int bf = *(const int*)(ws + OFF_FLAG);
    const int lane = threadIdx.x;  // 64
    float v = (partial[lane] - partial[128 + lane]) + (partial[lane + 64] - partial[192 + lane]);
    #pragma unroll
    for (int off = 32; off; off >>= 1) v += __shfl_xor(v, off);
    if (lane == 0) {
        const float mean = v / 128.f;
        if (bf) ((u16*)out)[0] = f2b(mean);
        else    ((float*)out)[0] = mean;
    }
}

extern "C" void kernel_launch(void* const* d_in, const int* in_sizes, int n_in,
                              void* d_out, int out_size, void* d_ws, size_t ws_size,
                              hipStream_t stream) {
    (void)in_sizes; (void)n_in; (void)out_size;
    if (ws_size < WS_NEED) return;
    unsigned char* ws = (unsigned char*)d_ws;

    const void* sent  = d_in[0];
    const void* tags  = d_in[1];
    const void* embed = d_in[3];

    u16* x0  = (u16*)(ws + OFF_X0);
    u16* h0  = (u16*)(ws + OFF_H0);
    u16* h1  = (u16*)(ws + OFF_H1);
    u16* Zb  = (u16*)(ws + OFF_Z);
    float* em = (float*)(ws + OFF_EM);
    float* part = (float*)(ws + OFF_PART);

    sniff_k<<<1, 64, 0, stream>>>((const unsigned char*)d_in[12], (int*)(ws + OFF_FLAG));
    prep_k<<<3102, 256, 0, stream>>>(d_in[4], d_in[5], d_in[6], d_in[7], d_in[8],
                                     d_in[9], d_in[10], d_in[11], d_in[12], d_in[13],
                                     d_in[14], ws);
    gather_k<<<4096, 256, 0, stream>>>(embed, (const int*)sent, ws);
    // layer 0
    gemm_k<128><<<256, 256, 0, stream>>>(x0, (const u16*)(ws + OFF_WIH0),
                                         (const float*)(ws + OFF_B0), Zb);
    scan_k<<<256, 256, 0, stream>>>(Zb, (const unsigned char*)(ws + OFF_WHH0F8), h0);
    // layer 1
    gemm_k<256><<<256, 256, 0, stream>>>(h0, (const u16*)(ws + OFF_WIH1),
                                         (const float*)(ws + OFF_B1), Zb);
    scan_k<<<256, 256, 0, stream>>>(Zb, (const unsigned char*)(ws + OFF_WHH1F8), h1);
    // emissions + CRF
    emis_k<<<256, 256, 0, stream>>>(h1, (const u16*)(ws + OFF_WOUT),
                                    (const float*)(ws + OFF_BOUT), em);
    crf_k<<<192, 64, 0, stream>>>(em, (const int*)tags,
                                  (const float*)(ws + OFF_TRANS),
                                  (const float*)(ws + OFF_START),
                                  (const float*)(ws + OFF_END), part);
    fin_k<<<1, 64, 0, stream>>>(part, d_out, ws);
}